// Round 15
// baseline (68.696 us; speedup 1.0000x reference)
//
#include <hip/hip_runtime.h>

#define D 256
#define W8 2048

// workspace float offsets (layout identical to R10 for embed)
#define WSC_OFF     20736             // 21 contiguous section-weight rows [k][d]
#define BPART_OFF   26112             // 4*256 bias partials
#define TB16_OFF    27392             // bf16 table: 81 rows * 256 ushort
// rows 0..52 card (pre-scaled 1/7), 53..61 hero, 62..70 acting, 71..80 nump

typedef float nf4 __attribute__((ext_vector_type(4)));  // native vec (nontemporal store)

__device__ __forceinline__ void f4acc(float4& a, const float4 b) {
    a.x += b.x; a.y += b.y; a.z += b.z; a.w += b.w;
}
__device__ __forceinline__ void f4fma(float4& a, float v, const float4 b) {
    a.x += v * b.x; a.y += v * b.y; a.z += v * b.z; a.w += v * b.w;
}

__device__ __forceinline__ ushort bf16rne(float v) {
    const unsigned x = __float_as_uint(v);
    return (ushort)((x + 0x7fffu + ((x >> 16) & 1u)) >> 16);
}

__device__ __forceinline__ float4 bf16x4(const ushort4 u) {
    float4 v;
    v.x = __uint_as_float((unsigned)u.x << 16);
    v.y = __uint_as_float((unsigned)u.y << 16);
    v.z = __uint_as_float((unsigned)u.z << 16);
    v.w = __uint_as_float((unsigned)u.w << 16);
    return v;
}

// -------- fuse v3: thread=d (no cross-lane reduce), multi-job W amortization
// R14 lesson: shuffle-reduce serializes (43 us). Old fuse: W reads fragment
// into 64 line-transactions/instr; 85 blocks x 4096 = 350K transactions.
// Here each block computes up to 10 output rows sharing one wblk W-slice:
// W value read once per d per k-chunk, FMA'd against 10 wave-uniform v's
// (table rows: contiguous float4; section cols: strided scalar -> SMEM).
// 15 blocks x ~4096 transactions = 61K total, ~2.5K cy VALU each.

#define FUSE3_BLOCKS 15

__global__ __launch_bounds__(256) void fuse3_kernel(
    const float* __restrict__ combine_W,
    const float* __restrict__ card_t, const float* __restrict__ hero_t,
    const float* __restrict__ act_t,  const float* __restrict__ nump_t,
    const float* __restrict__ scalar_W, const float* __restrict__ scalar_b,
    const float* __restrict__ blind_W,  const float* __restrict__ blind_b,
    const float* __restrict__ bet_W,    const float* __restrict__ bet_b,
    const float* __restrict__ action_W, const float* __restrict__ action_b,
    float* __restrict__ ws)
{
    const int bid = blockIdx.x;
    const int d   = threadIdx.x;

    ushort* tb  = (ushort*)(ws + TB16_OFF);
    float*  wsl = ws + WSC_OFF;
    float*  bpl = ws + BPART_OFF;

    float acc[10];
#pragma unroll
    for (int j = 0; j < 10; ++j) acc[j] = 0.f;

    if (bid <= 8) {
        // ---- table blocks: contiguous v rows, float4 reads ----
        const float* src; int wblk, nj, rowbase; float scale = 1.0f;
        if (bid < 6)       { src = card_t + bid * 9 * D; wblk = 0; nj = (bid == 5) ? 8 : 9;
                             rowbase = bid * 9; scale = 1.0f / 7.0f; }
        else if (bid == 6) { src = hero_t; wblk = 1; nj = 9;  rowbase = 53; }
        else if (bid == 7) { src = act_t;  wblk = 2; nj = 9;  rowbase = 62; }
        else               { src = nump_t; wblk = 6; nj = 10; rowbase = 71; }

        const float* wrow = combine_W + (size_t)d * W8 + wblk * D;
        for (int k = 0; k < D; k += 4) {
            const float4 w = *(const float4*)(wrow + k);
#pragma unroll
            for (int j = 0; j < 10; ++j) {
                if (j < nj) {
                    const float4 v = *(const float4*)(src + j * D + k);
                    acc[j] += w.x * v.x + w.y * v.y + w.z * v.z + w.w * v.w;
                }
            }
        }
#pragma unroll
        for (int j = 0; j < 10; ++j)
            if (j < nj) tb[(rowbase + j) * D + d] = bf16rne(acc[j] * scale);
    } else {
        // ---- section blocks: strided column reads + optional bias job ----
        const float* secW; const float* secB; int nk, col0, ncols, hasb, wbase, bprow, wblk;
        switch (bid) {
            case 9:  secW = scalar_W; secB = scalar_b; nk = 2; col0 = 0; ncols = 2; hasb = 1; wbase = 0;  bprow = 0; wblk = 3; break;
            case 10: secW = bet_W;    secB = bet_b;    nk = 9; col0 = 0; ncols = 5; hasb = 0; wbase = 2;  bprow = 1; wblk = 4; break;
            case 11: secW = bet_W;    secB = bet_b;    nk = 9; col0 = 5; ncols = 4; hasb = 1; wbase = 7;  bprow = 1; wblk = 4; break;
            case 12: secW = action_W; secB = action_b; nk = 8; col0 = 0; ncols = 4; hasb = 0; wbase = 11; bprow = 2; wblk = 5; break;
            case 13: secW = action_W; secB = action_b; nk = 8; col0 = 4; ncols = 4; hasb = 1; wbase = 15; bprow = 2; wblk = 5; break;
            default: secW = blind_W;  secB = blind_b;  nk = 2; col0 = 0; ncols = 2; hasb = 1; wbase = 19; bprow = 3; wblk = 7; break;
        }
        const int nj = ncols + hasb;
        const float* wrow = combine_W + (size_t)d * W8 + wblk * D;

        for (int k = 0; k < D; k += 4) {
            const float4 w = *(const float4*)(wrow + k);
#pragma unroll
            for (int j = 0; j < 6; ++j) {   // nj <= 6 in all section blocks
                if (j < nj) {
                    float v0, v1, v2, v3;
                    if (j < ncols) {
                        const float* p = secW + (size_t)k * nk + (col0 + j);
                        v0 = p[0]; v1 = p[nk]; v2 = p[2 * nk]; v3 = p[3 * nk];
                    } else {
                        v0 = secB[k]; v1 = secB[k + 1]; v2 = secB[k + 2]; v3 = secB[k + 3];
                    }
                    acc[j] += w.x * v0 + w.y * v1 + w.z * v2 + w.w * v3;
                }
            }
        }
#pragma unroll
        for (int j = 0; j < 6; ++j) {
            if (j < ncols)            wsl[(wbase + j) * D + d] = acc[j];
            else if (j < ncols + hasb) bpl[bprow * D + d] = acc[j];
        }
    }
}

// -------- main: EXACT R10 embed (best measured; 9 perturbations all lost) --
// R13 lesson: critical path punishes any added instruction.
// R11 lesson (3rd strike): never launch_bounds min-waves on this body.

#define EMB_BLOCKS 1024
#define EMB_THREADS 256
#define EMB_WAVES (EMB_THREADS / 64)
#define WROWS 22   // 21 weight rows + 1 fused-bias row

__global__ __launch_bounds__(EMB_THREADS) void embed_kernel(
    const int* __restrict__ cards,  const int* __restrict__ hero,
    const int* __restrict__ acting, const int* __restrict__ nump,
    const float* __restrict__ scalars, const float* __restrict__ blinds,
    const float* __restrict__ bets,    const float* __restrict__ action,
    const float* __restrict__ mask,    const float* __restrict__ combine_b,
    const float* __restrict__ ws, float* __restrict__ out, int ntok)
{
    __shared__ __align__(16) float wlds[WROWS * D];  // 22528 B

    const int tid = threadIdx.x;

    // rows 0..20: one contiguous slab ws[WSC_OFF .. WSC_OFF+21*256)
    {
        const float4* src = (const float4*)(ws + WSC_OFF);
        float4* dst = (float4*)wlds;
        for (int i = tid; i < 21 * (D / 4); i += EMB_THREADS) dst[i] = src[i];
        // row 21: fused bias = combine_b + 4 section-bias partials
        wlds[21 * D + tid] = combine_b[tid]
            + ws[BPART_OFF + 0 * D + tid] + ws[BPART_OFF + 1 * D + tid]
            + ws[BPART_OFF + 2 * D + tid] + ws[BPART_OFF + 3 * D + tid];
    }
    __syncthreads();

    const int lane = tid & 63;
    const int wave = tid >> 6;
    const int d0 = lane * 4;

    const ushort* tbg = (const ushort*)(ws + TB16_OFF);  // 81-row bf16 gather table

    const int gw = blockIdx.x * EMB_WAVES + wave;
    const int nw = EMB_BLOCKS * EMB_WAVES;

    for (int tok = gw; tok < ntok; tok += nw) {
        float4 acc0 = *(const float4*)(wlds + 21 * D + d0);  // bias + gathers
        float4 acc1 = {0.f, 0.f, 0.f, 0.f};                  // sections

        // bf16 gathers (8B/lane) from L2-resident table
        const int* cp = cards + (size_t)tok * 7;
#pragma unroll
        for (int j = 0; j < 7; ++j)
            f4acc(acc0, bf16x4(*(const ushort4*)(tbg + cp[j] * D + d0)));
        f4acc(acc0, bf16x4(*(const ushort4*)(tbg + (53 + hero[tok])   * D + d0)));
        f4acc(acc0, bf16x4(*(const ushort4*)(tbg + (62 + acting[tok]) * D + d0)));
        f4acc(acc0, bf16x4(*(const ushort4*)(tbg + (71 + nump[tok])   * D + d0)));

        // contiguous feature loads
        const float2 fs = *(const float2*)(scalars + (size_t)tok * 2);
        f4fma(acc1, fs.x, *(const float4*)(wlds + 0 * D + d0));
        f4fma(acc1, fs.y, *(const float4*)(wlds + 1 * D + d0));

        const float* fb = bets + (size_t)tok * 9;
#pragma unroll
        for (int k = 0; k < 9; ++k)
            f4fma(acc1, fb[k], *(const float4*)(wlds + (2 + k) * D + d0));

        const float4 fa0 = *(const float4*)(action + (size_t)tok * 8);
        const float4 fa1 = *(const float4*)(action + (size_t)tok * 8 + 4);
        f4fma(acc1, fa0.x, *(const float4*)(wlds + 11 * D + d0));
        f4fma(acc1, fa0.y, *(const float4*)(wlds + 12 * D + d0));
        f4fma(acc1, fa0.z, *(const float4*)(wlds + 13 * D + d0));
        f4fma(acc1, fa0.w, *(const float4*)(wlds + 14 * D + d0));
        f4fma(acc1, fa1.x, *(const float4*)(wlds + 15 * D + d0));
        f4fma(acc1, fa1.y, *(const float4*)(wlds + 16 * D + d0));
        f4fma(acc1, fa1.z, *(const float4*)(wlds + 17 * D + d0));
        f4fma(acc1, fa1.w, *(const float4*)(wlds + 18 * D + d0));

        const float2 fl = *(const float2*)(blinds + (size_t)tok * 2);
        f4fma(acc1, fl.x, *(const float4*)(wlds + 19 * D + d0));
        f4fma(acc1, fl.y, *(const float4*)(wlds + 20 * D + d0));

        const float m = mask[tok];
        nf4 o;
        o.x = (acc0.x + acc1.x) * m; o.y = (acc0.y + acc1.y) * m;
        o.z = (acc0.z + acc1.z) * m; o.w = (acc0.w + acc1.w) * m;
        __builtin_nontemporal_store(o, (nf4*)(out + (size_t)tok * D + d0));
    }
}

extern "C" void kernel_launch(void* const* d_in, const int* in_sizes, int n_in,
                              void* d_out, int out_size, void* d_ws, size_t ws_size,
                              hipStream_t stream) {
    const int*   cards    = (const int*)d_in[0];
    const int*   hero     = (const int*)d_in[1];
    const int*   acting   = (const int*)d_in[2];
    const int*   nump     = (const int*)d_in[3];
    const float* scalars  = (const float*)d_in[4];
    const float* blinds   = (const float*)d_in[5];
    const float* bets     = (const float*)d_in[6];
    const float* action   = (const float*)d_in[7];
    const float* mask     = (const float*)d_in[8];
    const float* card_t   = (const float*)d_in[9];
    const float* hero_t   = (const float*)d_in[10];
    const float* act_t    = (const float*)d_in[11];
    const float* nump_t   = (const float*)d_in[12];
    const float* scalar_W = (const float*)d_in[13];
    const float* scalar_b = (const float*)d_in[14];
    const float* blind_W  = (const float*)d_in[15];
    const float* blind_b  = (const float*)d_in[16];
    const float* bet_W    = (const float*)d_in[17];
    const float* bet_b    = (const float*)d_in[18];
    const float* action_W = (const float*)d_in[19];
    const float* action_b = (const float*)d_in[20];
    const float* combine_W= (const float*)d_in[21];
    const float* combine_b= (const float*)d_in[22];

    float* ws  = (float*)d_ws;
    float* out = (float*)d_out;
    const int ntok = in_sizes[1];  // B*S (hero_pos flat count)

    hipLaunchKernelGGL(fuse3_kernel, dim3(FUSE3_BLOCKS), dim3(256), 0, stream,
                       combine_W, card_t, hero_t, act_t, nump_t,
                       scalar_W, scalar_b, blind_W, blind_b, bet_W, bet_b,
                       action_W, action_b, ws);
    hipLaunchKernelGGL(embed_kernel, dim3(EMB_BLOCKS), dim3(EMB_THREADS), 0, stream,
                       cards, hero, acting, nump, scalars, blinds, bets, action, mask,
                       combine_b, ws, out, ntok);
}

// Round 16
// 49.345 us; speedup vs baseline: 1.3921x; 1.3921x over previous
//
#include <hip/hip_runtime.h>

#define D 256
#define W8 2048

// workspace float offsets (layout identical to R10 for embed)
#define WSC_OFF     20736             // 21 contiguous section-weight rows [k][d]
#define WBET_OFF    21248
#define WACT_OFF    23552
#define WBL_OFF     25600
#define BPART_OFF   26112             // 4*256 bias partials
#define TB16_OFF    27392             // bf16 table: 81 rows * 256 ushort
// rows 0..52 card (pre-scaled 1/7), 53..61 hero, 62..70 acting, 71..80 nump

typedef float nf4 __attribute__((ext_vector_type(4)));  // native vec (nontemporal store)

__device__ __forceinline__ void f4acc(float4& a, const float4 b) {
    a.x += b.x; a.y += b.y; a.z += b.z; a.w += b.w;
}
__device__ __forceinline__ void f4fma(float4& a, float v, const float4 b) {
    a.x += v * b.x; a.y += v * b.y; a.z += v * b.z; a.w += v * b.w;
}

__device__ __forceinline__ ushort bf16rne(float v) {
    const unsigned x = __float_as_uint(v);
    return (ushort)((x + 0x7fffu + ((x >> 16) & 1u)) >> 16);
}

__device__ __forceinline__ float4 bf16x4(const ushort4 u) {
    float4 v;
    v.x = __uint_as_float((unsigned)u.x << 16);
    v.y = __uint_as_float((unsigned)u.y << 16);
    v.z = __uint_as_float((unsigned)u.z << 16);
    v.w = __uint_as_float((unsigned)u.w << 16);
    return v;
}

// -------- fuse: d-split 4x (R13's variant, UNCONFOUNDED this time) ---------
// Bench-level subtraction (R14/R15 vs R10) shows fuse_old ~20-25 us — the
// BIGGER half of the 39.2. This spreads its 1.4M uncoalesced L1 transactions
// over 340 blocks (~256 CUs) instead of 85. Per-thread work unchanged.

template <int NK>
__device__ void fuse_section(const float* __restrict__ combine_W, int wblk,
                             const float* __restrict__ sw,   // LDS [NK][D]
                             const float* __restrict__ sb,   // LDS [D]
                             float* __restrict__ dstT,       // ws [NK][D]
                             float* __restrict__ bpart,      // ws [D]
                             int d)
{
    float acc[NK];
#pragma unroll
    for (int k = 0; k < NK; ++k) acc[k] = 0.f;
    float accb = 0.f;
    const float* wrow = combine_W + (size_t)d * W8 + wblk * D;
    for (int dd = 0; dd < D; dd += 4) {
        float4 w = *(const float4*)(wrow + dd);
        accb += w.x * sb[dd] + w.y * sb[dd + 1] + w.z * sb[dd + 2] + w.w * sb[dd + 3];
#pragma unroll
        for (int k = 0; k < NK; ++k) {
            const float* s = sw + k * D + dd;
            acc[k] += w.x * s[0] + w.y * s[1] + w.z * s[2] + w.w * s[3];
        }
    }
#pragma unroll
    for (int k = 0; k < NK; ++k) dstT[k * D + d] = acc[k];
    bpart[d] = accb;
}

__global__ __launch_bounds__(64) void fuse_kernel(
    const float* __restrict__ combine_W,
    const float* __restrict__ card_t, const float* __restrict__ hero_t,
    const float* __restrict__ act_t,  const float* __restrict__ nump_t,
    const float* __restrict__ scalar_W, const float* __restrict__ scalar_b,
    const float* __restrict__ blind_W,  const float* __restrict__ blind_b,
    const float* __restrict__ bet_W,    const float* __restrict__ bet_b,
    const float* __restrict__ action_W, const float* __restrict__ action_b,
    float* __restrict__ ws)
{
    __shared__ float sh[10 * D];  // 10 KB
    const int unit = blockIdx.x >> 2;
    const int dq   = blockIdx.x & 3;
    const int tid  = threadIdx.x;          // 0..63
    const int d    = dq * 64 + tid;        // this block's d-slice

    if (unit < 81) {
        const float* src; int wblk; float scale;
        if (unit < 53)      { src = card_t + unit * D;        wblk = 0; scale = 1.0f / 7.0f; }
        else if (unit < 62) { src = hero_t + (unit - 53) * D; wblk = 1; scale = 1.0f; }
        else if (unit < 71) { src = act_t  + (unit - 62) * D; wblk = 2; scale = 1.0f; }
        else                { src = nump_t + (unit - 71) * D; wblk = 6; scale = 1.0f; }
#pragma unroll
        for (int i = 0; i < 4; ++i) sh[tid + i * 64] = src[tid + i * 64];
        __syncthreads();
        const float* wrow = combine_W + (size_t)d * W8 + wblk * D;
        float a0 = 0.f, a1 = 0.f, a2 = 0.f, a3 = 0.f;
#pragma unroll 8
        for (int k = 0; k < D; k += 4) {
            float4 w = *(const float4*)(wrow + k);
            a0 += w.x * sh[k];     a1 += w.y * sh[k + 1];
            a2 += w.z * sh[k + 2]; a3 += w.w * sh[k + 3];
        }
        const float v = ((a0 + a1) + (a2 + a3)) * scale;
        ((ushort*)(ws + TB16_OFF))[unit * D + d] = bf16rne(v);
    } else {
        const int sec = unit - 81;
        const float* secW; const float* secB; int nk, wblk; float* dstT;
        switch (sec) {
            case 0:  secW = scalar_W; secB = scalar_b; nk = 2; wblk = 3; dstT = ws + WSC_OFF;  break;
            case 1:  secW = bet_W;    secB = bet_b;    nk = 9; wblk = 4; dstT = ws + WBET_OFF; break;
            case 2:  secW = action_W; secB = action_b; nk = 8; wblk = 5; dstT = ws + WACT_OFF; break;
            default: secW = blind_W;  secB = blind_b;  nk = 2; wblk = 7; dstT = ws + WBL_OFF;  break;
        }
        for (int k = 0; k < nk; ++k)
#pragma unroll
            for (int i = 0; i < 4; ++i)
                sh[k * D + tid + i * 64] = secW[(tid + i * 64) * nk + k];  // transpose
#pragma unroll
        for (int i = 0; i < 4; ++i) sh[9 * D + tid + i * 64] = secB[tid + i * 64];
        __syncthreads();
        float* bpart = ws + BPART_OFF + sec * D;
        if (nk == 2)      fuse_section<2>(combine_W, wblk, sh, sh + 9 * D, dstT, bpart, d);
        else if (nk == 8) fuse_section<8>(combine_W, wblk, sh, sh + 9 * D, dstT, bpart, d);
        else              fuse_section<9>(combine_W, wblk, sh, sh + 9 * D, dstT, bpart, d);
    }
}

// -------- main: EXACT R10 embed (best measured) ----------------------------
// R13 lesson: critical path punishes any added instruction (bf16-LDS weights
// cost +9us). R11 lesson (3rd strike): never launch_bounds min-waves here.

#define EMB_BLOCKS 1024
#define EMB_THREADS 256
#define EMB_WAVES (EMB_THREADS / 64)
#define WROWS 22   // 21 weight rows + 1 fused-bias row

__global__ __launch_bounds__(EMB_THREADS) void embed_kernel(
    const int* __restrict__ cards,  const int* __restrict__ hero,
    const int* __restrict__ acting, const int* __restrict__ nump,
    const float* __restrict__ scalars, const float* __restrict__ blinds,
    const float* __restrict__ bets,    const float* __restrict__ action,
    const float* __restrict__ mask,    const float* __restrict__ combine_b,
    const float* __restrict__ ws, float* __restrict__ out, int ntok)
{
    __shared__ __align__(16) float wlds[WROWS * D];  // 22528 B

    const int tid = threadIdx.x;

    {
        const float4* src = (const float4*)(ws + WSC_OFF);
        float4* dst = (float4*)wlds;
        for (int i = tid; i < 21 * (D / 4); i += EMB_THREADS) dst[i] = src[i];
        wlds[21 * D + tid] = combine_b[tid]
            + ws[BPART_OFF + 0 * D + tid] + ws[BPART_OFF + 1 * D + tid]
            + ws[BPART_OFF + 2 * D + tid] + ws[BPART_OFF + 3 * D + tid];
    }
    __syncthreads();

    const int lane = tid & 63;
    const int wave = tid >> 6;
    const int d0 = lane * 4;

    const ushort* tbg = (const ushort*)(ws + TB16_OFF);

    const int gw = blockIdx.x * EMB_WAVES + wave;
    const int nw = EMB_BLOCKS * EMB_WAVES;

    for (int tok = gw; tok < ntok; tok += nw) {
        float4 acc0 = *(const float4*)(wlds + 21 * D + d0);  // bias + gathers
        float4 acc1 = {0.f, 0.f, 0.f, 0.f};                  // sections

        const int* cp = cards + (size_t)tok * 7;
#pragma unroll
        for (int j = 0; j < 7; ++j)
            f4acc(acc0, bf16x4(*(const ushort4*)(tbg + cp[j] * D + d0)));
        f4acc(acc0, bf16x4(*(const ushort4*)(tbg + (53 + hero[tok])   * D + d0)));
        f4acc(acc0, bf16x4(*(const ushort4*)(tbg + (62 + acting[tok]) * D + d0)));
        f4acc(acc0, bf16x4(*(const ushort4*)(tbg + (71 + nump[tok])   * D + d0)));

        const float2 fs = *(const float2*)(scalars + (size_t)tok * 2);
        f4fma(acc1, fs.x, *(const float4*)(wlds + 0 * D + d0));
        f4fma(acc1, fs.y, *(const float4*)(wlds + 1 * D + d0));

        const float* fb = bets + (size_t)tok * 9;
#pragma unroll
        for (int k = 0; k < 9; ++k)
            f4fma(acc1, fb[k], *(const float4*)(wlds + (2 + k) * D + d0));

        const float4 fa0 = *(const float4*)(action + (size_t)tok * 8);
        const float4 fa1 = *(const float4*)(action + (size_t)tok * 8 + 4);
        f4fma(acc1, fa0.x, *(const float4*)(wlds + 11 * D + d0));
        f4fma(acc1, fa0.y, *(const float4*)(wlds + 12 * D + d0));
        f4fma(acc1, fa0.z, *(const float4*)(wlds + 13 * D + d0));
        f4fma(acc1, fa0.w, *(const float4*)(wlds + 14 * D + d0));
        f4fma(acc1, fa1.x, *(const float4*)(wlds + 15 * D + d0));
        f4fma(acc1, fa1.y, *(const float4*)(wlds + 16 * D + d0));
        f4fma(acc1, fa1.z, *(const float4*)(wlds + 17 * D + d0));
        f4fma(acc1, fa1.w, *(const float4*)(wlds + 18 * D + d0));

        const float2 fl = *(const float2*)(blinds + (size_t)tok * 2);
        f4fma(acc1, fl.x, *(const float4*)(wlds + 19 * D + d0));
        f4fma(acc1, fl.y, *(const float4*)(wlds + 20 * D + d0));

        const float m = mask[tok];
        nf4 o;
        o.x = (acc0.x + acc1.x) * m; o.y = (acc0.y + acc1.y) * m;
        o.z = (acc0.z + acc1.z) * m; o.w = (acc0.w + acc1.w) * m;
        __builtin_nontemporal_store(o, (nf4*)(out + (size_t)tok * D + d0));
    }
}

extern "C" void kernel_launch(void* const* d_in, const int* in_sizes, int n_in,
                              void* d_out, int out_size, void* d_ws, size_t ws_size,
                              hipStream_t stream) {
    const int*   cards    = (const int*)d_in[0];
    const int*   hero     = (const int*)d_in[1];
    const int*   acting   = (const int*)d_in[2];
    const int*   nump     = (const int*)d_in[3];
    const float* scalars  = (const float*)d_in[4];
    const float* blinds   = (const float*)d_in[5];
    const float* bets     = (const float*)d_in[6];
    const float* action   = (const float*)d_in[7];
    const float* mask     = (const float*)d_in[8];
    const float* card_t   = (const float*)d_in[9];
    const float* hero_t   = (const float*)d_in[10];
    const float* act_t    = (const float*)d_in[11];
    const float* nump_t   = (const float*)d_in[12];
    const float* scalar_W = (const float*)d_in[13];
    const float* scalar_b = (const float*)d_in[14];
    const float* blind_W  = (const float*)d_in[15];
    const float* blind_b  = (const float*)d_in[16];
    const float* bet_W    = (const float*)d_in[17];
    const float* bet_b    = (const float*)d_in[18];
    const float* action_W = (const float*)d_in[19];
    const float* action_b = (const float*)d_in[20];
    const float* combine_W= (const float*)d_in[21];
    const float* combine_b= (const float*)d_in[22];

    float* ws  = (float*)d_ws;
    float* out = (float*)d_out;
    const int ntok = in_sizes[1];  // B*S (hero_pos flat count)

    hipLaunchKernelGGL(fuse_kernel, dim3(85 * 4), dim3(64), 0, stream,
                       combine_W, card_t, hero_t, act_t, nump_t,
                       scalar_W, scalar_b, blind_W, blind_b, bet_W, bet_b,
                       action_W, action_b, ws);
    hipLaunchKernelGGL(embed_kernel, dim3(EMB_BLOCKS), dim3(EMB_THREADS), 0, stream,
                       cards, hero, acting, nump, scalars, blinds, bets, action, mask,
                       combine_b, ws, out, ntok);
}

// Round 17
// 37.668 us; speedup vs baseline: 1.8237x; 1.3100x over previous
//
#include <hip/hip_runtime.h>

#define D 256
#define W8 2048

// workspace float offsets (layout identical to R10 for embed)
#define WSC_OFF     20736             // 21 contiguous section-weight rows [k][d]
#define BPART_OFF   26112             // 4*256 bias partials
#define TB16_OFF    27392             // bf16 table: 81 rows * 256 ushort
// rows 0..52 card (pre-scaled 1/7), 53..61 hero, 62..70 acting, 71..80 nump

typedef float nf4 __attribute__((ext_vector_type(4)));  // native vec (nontemporal store)

__device__ __forceinline__ void f4acc(float4& a, const float4 b) {
    a.x += b.x; a.y += b.y; a.z += b.z; a.w += b.w;
}
__device__ __forceinline__ void f4fma(float4& a, float v, const float4 b) {
    a.x += v * b.x; a.y += v * b.y; a.z += v * b.z; a.w += v * b.w;
}

__device__ __forceinline__ ushort bf16rne(float v) {
    const unsigned x = __float_as_uint(v);
    return (ushort)((x + 0x7fffu + ((x >> 16) & 1u)) >> 16);
}

__device__ __forceinline__ float4 bf16x4(const ushort4 u) {
    float4 v;
    v.x = __uint_as_float((unsigned)u.x << 16);
    v.y = __uint_as_float((unsigned)u.y << 16);
    v.z = __uint_as_float((unsigned)u.z << 16);
    v.w = __uint_as_float((unsigned)u.w << 16);
    return v;
}

// -------- fuse v5: coalesced k-tiled LDS staging of W, thread=d, 106 jobs --
// The defect in ALL prior fuses: thread=d reads W[d][k] at 8KB lane stride
// (64 lines per wave instr, 1.4M line transactions). Here W is staged through
// LDS in [256d][32k] tiles with fully-coalesced global reads (16 full lines
// per instr, zero overfetch), then read from LDS with pad-33 rows
// (bank = (d+kk) mod 32 -> conflict-free). One row-job per block (fuse2's
// verified job mapping); 106 blocks -> <=1 per CU.

__global__ __launch_bounds__(256) void fuse5_kernel(
    const float* __restrict__ combine_W,
    const float* __restrict__ card_t, const float* __restrict__ hero_t,
    const float* __restrict__ act_t,  const float* __restrict__ nump_t,
    const float* __restrict__ scalar_W, const float* __restrict__ scalar_b,
    const float* __restrict__ blind_W,  const float* __restrict__ blind_b,
    const float* __restrict__ bet_W,    const float* __restrict__ bet_b,
    const float* __restrict__ action_W, const float* __restrict__ action_b,
    float* __restrict__ ws)
{
    __shared__ float vsh[D];                 // the v row (wave-uniform reads)
    __shared__ float Wl[D * 33];             // k-tile [256 d][32 k], pad 33

    const int job = blockIdx.x;   // 0..105
    const int tid = threadIdx.x;

    int wblk;
    float scale = 1.0f;
    int kind;                     // 0=bf16 table row, 1=f32 weight row, 2=bias partial
    int orow;

    if (job < 81) {
        kind = 0; orow = job;
        const float* src;
        if (job < 53)      { src = card_t + job * D;        wblk = 0; scale = 1.0f / 7.0f; }
        else if (job < 62) { src = hero_t + (job - 53) * D; wblk = 1; }
        else if (job < 71) { src = act_t  + (job - 62) * D; wblk = 2; }
        else               { src = nump_t + (job - 71) * D; wblk = 6; }
        vsh[tid] = src[tid];
    } else if (job < 102) {
        kind = 1; orow = job - 81;            // 0..20 in the WSC slab
        const float* secW; int nk, k;
        if (orow < 2)       { secW = scalar_W; nk = 2; k = orow;      wblk = 3; }
        else if (orow < 11) { secW = bet_W;    nk = 9; k = orow - 2;  wblk = 4; }
        else if (orow < 19) { secW = action_W; nk = 8; k = orow - 11; wblk = 5; }
        else                { secW = blind_W;  nk = 2; k = orow - 19; wblk = 7; }
        vsh[tid] = secW[tid * nk + k];        // column k of [D x nk] torch weight
    } else {
        kind = 2; orow = job - 102;           // 0..3 bias partials
        const float* secB;
        switch (orow) {
            case 0:  secB = scalar_b; wblk = 3; break;
            case 1:  secB = bet_b;    wblk = 4; break;
            case 2:  secB = action_b; wblk = 5; break;
            default: secB = blind_b;  wblk = 7; break;
        }
        vsh[tid] = secB[tid];
    }

    const float* Wbase = combine_W + wblk * D;   // row d at Wbase + d*W8
    float acc = 0.f;

    for (int t = 0; t < 8; ++t) {                // 8 k-tiles of 32
        const int k0 = t * 32;
        __syncthreads();                         // prev tile consumed (t=0: vsh visible)
        // coalesced stage: 2048 float4 per tile, 8 per thread
#pragma unroll
        for (int i = 0; i < 8; ++i) {
            const int fidx = tid + i * 256;
            const int dd = fidx >> 3;
            const int kq = (fidx & 7) * 4;
            const float4 w = *(const float4*)(Wbase + (size_t)dd * W8 + k0 + kq);
            float* p = Wl + dd * 33 + kq;        // scalar writes: bank (dd+kq+c)%32, ~2-way
            p[0] = w.x; p[1] = w.y; p[2] = w.z; p[3] = w.w;
        }
        __syncthreads();                         // stage visible
        // compute: thread=d, conflict-free scalar reads + uniform v broadcasts
        const float* wrow = Wl + tid * 33;
#pragma unroll
        for (int kk = 0; kk < 32; kk += 4) {
            const float4 vv = *(const float4*)(vsh + k0 + kk);   // uniform -> broadcast
            acc += wrow[kk]     * vv.x + wrow[kk + 1] * vv.y
                 + wrow[kk + 2] * vv.z + wrow[kk + 3] * vv.w;
        }
    }

    ushort* tb  = (ushort*)(ws + TB16_OFF);
    float*  wsl = ws + WSC_OFF;
    float*  bpl = ws + BPART_OFF;
    if (kind == 0)      tb[orow * D + tid] = bf16rne(acc * scale);
    else if (kind == 1) wsl[orow * D + tid] = acc;
    else                bpl[orow * D + tid] = acc;
}

// -------- main: EXACT R10 embed (best measured) ----------------------------
// R13/R16 lesson: embed is at a sharp local optimum — do not touch.
// R11 lesson (3rd strike): never launch_bounds min-waves on this body.

#define EMB_BLOCKS 1024
#define EMB_THREADS 256
#define EMB_WAVES (EMB_THREADS / 64)
#define WROWS 22   // 21 weight rows + 1 fused-bias row

__global__ __launch_bounds__(EMB_THREADS) void embed_kernel(
    const int* __restrict__ cards,  const int* __restrict__ hero,
    const int* __restrict__ acting, const int* __restrict__ nump,
    const float* __restrict__ scalars, const float* __restrict__ blinds,
    const float* __restrict__ bets,    const float* __restrict__ action,
    const float* __restrict__ mask,    const float* __restrict__ combine_b,
    const float* __restrict__ ws, float* __restrict__ out, int ntok)
{
    __shared__ __align__(16) float wlds[WROWS * D];  // 22528 B

    const int tid = threadIdx.x;

    {
        const float4* src = (const float4*)(ws + WSC_OFF);
        float4* dst = (float4*)wlds;
        for (int i = tid; i < 21 * (D / 4); i += EMB_THREADS) dst[i] = src[i];
        wlds[21 * D + tid] = combine_b[tid]
            + ws[BPART_OFF + 0 * D + tid] + ws[BPART_OFF + 1 * D + tid]
            + ws[BPART_OFF + 2 * D + tid] + ws[BPART_OFF + 3 * D + tid];
    }
    __syncthreads();

    const int lane = tid & 63;
    const int wave = tid >> 6;
    const int d0 = lane * 4;

    const ushort* tbg = (const ushort*)(ws + TB16_OFF);

    const int gw = blockIdx.x * EMB_WAVES + wave;
    const int nw = EMB_BLOCKS * EMB_WAVES;

    for (int tok = gw; tok < ntok; tok += nw) {
        float4 acc0 = *(const float4*)(wlds + 21 * D + d0);  // bias + gathers
        float4 acc1 = {0.f, 0.f, 0.f, 0.f};                  // sections

        const int* cp = cards + (size_t)tok * 7;
#pragma unroll
        for (int j = 0; j < 7; ++j)
            f4acc(acc0, bf16x4(*(const ushort4*)(tbg + cp[j] * D + d0)));
        f4acc(acc0, bf16x4(*(const ushort4*)(tbg + (53 + hero[tok])   * D + d0)));
        f4acc(acc0, bf16x4(*(const ushort4*)(tbg + (62 + acting[tok]) * D + d0)));
        f4acc(acc0, bf16x4(*(const ushort4*)(tbg + (71 + nump[tok])   * D + d0)));

        const float2 fs = *(const float2*)(scalars + (size_t)tok * 2);
        f4fma(acc1, fs.x, *(const float4*)(wlds + 0 * D + d0));
        f4fma(acc1, fs.y, *(const float4*)(wlds + 1 * D + d0));

        const float* fb = bets + (size_t)tok * 9;
#pragma unroll
        for (int k = 0; k < 9; ++k)
            f4fma(acc1, fb[k], *(const float4*)(wlds + (2 + k) * D + d0));

        const float4 fa0 = *(const float4*)(action + (size_t)tok * 8);
        const float4 fa1 = *(const float4*)(action + (size_t)tok * 8 + 4);
        f4fma(acc1, fa0.x, *(const float4*)(wlds + 11 * D + d0));
        f4fma(acc1, fa0.y, *(const float4*)(wlds + 12 * D + d0));
        f4fma(acc1, fa0.z, *(const float4*)(wlds + 13 * D + d0));
        f4fma(acc1, fa0.w, *(const float4*)(wlds + 14 * D + d0));
        f4fma(acc1, fa1.x, *(const float4*)(wlds + 15 * D + d0));
        f4fma(acc1, fa1.y, *(const float4*)(wlds + 16 * D + d0));
        f4fma(acc1, fa1.z, *(const float4*)(wlds + 17 * D + d0));
        f4fma(acc1, fa1.w, *(const float4*)(wlds + 18 * D + d0));

        const float2 fl = *(const float2*)(blinds + (size_t)tok * 2);
        f4fma(acc1, fl.x, *(const float4*)(wlds + 19 * D + d0));
        f4fma(acc1, fl.y, *(const float4*)(wlds + 20 * D + d0));

        const float m = mask[tok];
        nf4 o;
        o.x = (acc0.x + acc1.x) * m; o.y = (acc0.y + acc1.y) * m;
        o.z = (acc0.z + acc1.z) * m; o.w = (acc0.w + acc1.w) * m;
        __builtin_nontemporal_store(o, (nf4*)(out + (size_t)tok * D + d0));
    }
}

extern "C" void kernel_launch(void* const* d_in, const int* in_sizes, int n_in,
                              void* d_out, int out_size, void* d_ws, size_t ws_size,
                              hipStream_t stream) {
    const int*   cards    = (const int*)d_in[0];
    const int*   hero     = (const int*)d_in[1];
    const int*   acting   = (const int*)d_in[2];
    const int*   nump     = (const int*)d_in[3];
    const float* scalars  = (const float*)d_in[4];
    const float* blinds   = (const float*)d_in[5];
    const float* bets     = (const float*)d_in[6];
    const float* action   = (const float*)d_in[7];
    const float* mask     = (const float*)d_in[8];
    const float* card_t   = (const float*)d_in[9];
    const float* hero_t   = (const float*)d_in[10];
    const float* act_t    = (const float*)d_in[11];
    const float* nump_t   = (const float*)d_in[12];
    const float* scalar_W = (const float*)d_in[13];
    const float* scalar_b = (const float*)d_in[14];
    const float* blind_W  = (const float*)d_in[15];
    const float* blind_b  = (const float*)d_in[16];
    const float* bet_W    = (const float*)d_in[17];
    const float* bet_b    = (const float*)d_in[18];
    const float* action_W = (const float*)d_in[19];
    const float* action_b = (const float*)d_in[20];
    const float* combine_W= (const float*)d_in[21];
    const float* combine_b= (const float*)d_in[22];

    float* ws  = (float*)d_ws;
    float* out = (float*)d_out;
    const int ntok = in_sizes[1];  // B*S (hero_pos flat count)

    hipLaunchKernelGGL(fuse5_kernel, dim3(106), dim3(256), 0, stream,
                       combine_W, card_t, hero_t, act_t, nump_t,
                       scalar_W, scalar_b, blind_W, blind_b, bet_W, bet_b,
                       action_W, action_b, ws);
    hipLaunchKernelGGL(embed_kernel, dim3(EMB_BLOCKS), dim3(EMB_THREADS), 0, stream,
                       cards, hero, acting, nump, scalars, blinds, bets, action, mask,
                       combine_b, ws, out, ntok);
}